// Round 9
// baseline (327.780 us; speedup 1.0000x reference)
//
#include <hip/hip_runtime.h>
#include <hip/hip_fp16.h>

#define N_NODES 50000
#define N_EDGES 800000
#define IN_F    512
#define NH      4
#define DH      64
#define HD      256   // NH*DH
#define NEG     0.2f
#define MAXDEG  64    // Poisson(16) max degree bound: P(any node > 64) ~ e^-40 * 5e4 ~ 0
#define NWAVES  (N_NODES / 16)   // 3125 independent gemm waves (exact)

typedef __attribute__((ext_vector_type(8))) short bf16x8;
typedef __attribute__((ext_vector_type(4))) float f32x4;

__device__ __forceinline__ unsigned short f2bf(float x) {
    unsigned u = __float_as_uint(x);
    unsigned r = (u + 0x7FFFu + ((u >> 16) & 1u)) >> 16;  // RNE
    return (unsigned short)r;
}
__device__ __forceinline__ float bf2f(unsigned short b) {
    return __uint_as_float((unsigned)b << 16);
}
__device__ __forceinline__ unsigned short f2h(float x) {
    __half h = __float2half_rn(x);
    return *(unsigned short*)&h;
}
__device__ __forceinline__ float h2f(unsigned short us) {
    __half h = *(__half*)&us;
    return __half2float(h);
}

// ---------------- setup: zero counts + W -> WtbT (granule-major) --------------
// WtbT layout: K-tile t (0..7), granule g = (k&63)/8 (0..7), col n (0..255),
// 8 shorts. A wave's B-fragment load (16 lanes x consecutive n) is a
// contiguous 256B segment -> coalesced, L2-hot direct-to-register loads.
#define NZB ((N_NODES + 255) / 256)   // 196 zero chunks
__global__ __launch_bounds__(256) void setup_kernel(const float* __restrict__ W,
                                                    unsigned short* __restrict__ WtbT,
                                                    int* __restrict__ counts) {
    int b = blockIdx.x;
    if (b < NZB) {
        int i = b * 256 + threadIdx.x;
        if (i < N_NODES) counts[i] = 0;
    } else {
        int i = (b - NZB) * 256 + threadIdx.x;   // over 512*256
        if (i < IN_F * HD) {
            int k = i >> 8;        // 0..511
            int n = i & 255;       // 0..255
            int t  = k >> 6;       // k-tile
            int kk = k & 63;
            int g  = kk >> 3;      // 8-elem granule within tile
            int w8 = kk & 7;
            WtbT[(size_t)t * 16384 + g * 2048 + n * 8 + w8] = f2bf(W[i]);
        }
    }
}

// ---------------- bf16 MFMA GEMM: ftb = bf16(feat @ W), el/er fused -----------
// BARRIER-FREE / LDS-FREE: each wave independently owns 16 rows x 256 cols
// (50000 = 3125 x 16 exact). A rows are wave-private -> register-direct from
// HBM (read exactly once); B register-direct from the L2-hot 256KB WtbT.
// acc[16] f32x4. vmcnt discipline per K-tile: drain A at tile top (convert),
// issue B chunks mod-3 triple-buffered (lookahead 2, compile-time indices),
// issue next A AFTER the last B issue so all B waits are counted and A's
// ~900cy HBM latency hides under 6 chunk-waits + 32 MFMAs. Waves slip freely:
// no lockstep, occupancy VGPR-bound (~12 waves/CU = grid's 3125/256).
__global__ __launch_bounds__(256) void gemm_kernel(const float* __restrict__ A,
                                                   const unsigned short* __restrict__ WtbT,
                                                   const float* __restrict__ attn_l,
                                                   const float* __restrict__ attn_r,
                                                   unsigned short* __restrict__ Cb,
                                                   float* __restrict__ el,
                                                   float* __restrict__ er) {
    const int tid  = threadIdx.x;
    const int wv   = (blockIdx.x * 256 + tid) >> 6;   // global wave id
    if (wv >= NWAVES) return;
    const int lane = tid & 63;
    const int lm   = lane & 15;      // A-row / B-col lane
    const int quad = lane >> 4;      // k-granule

    const int row0 = wv * 16;        // this wave's 16 rows (exact, no guard)
    const float* arow = A + (size_t)(row0 + lm) * IN_F + quad * 8;
    const unsigned short* bbase = WtbT + quad * 2048 + (size_t)lm * 8;

    f32x4 acc[16] = {};
    float4 pa0, pa1, pa2, pa3;       // A fp32 (current tile), HBM
    bf16x8 bch[3][4];                // B triple-buffered chunks (L2)

    // prologue: A for tile 0
    pa0 = *(const float4*)(arow + 0);
    pa1 = *(const float4*)(arow + 4);
    pa2 = *(const float4*)(arow + 32);
    pa3 = *(const float4*)(arow + 36);

    for (int t = 0; t < 8; t++) {
        // convert A (vmcnt drains pa here; queue is then clean for B)
        bf16x8 af0, af1;
        af0[0] = (short)f2bf(pa0.x); af0[1] = (short)f2bf(pa0.y);
        af0[2] = (short)f2bf(pa0.z); af0[3] = (short)f2bf(pa0.w);
        af0[4] = (short)f2bf(pa1.x); af0[5] = (short)f2bf(pa1.y);
        af0[6] = (short)f2bf(pa1.z); af0[7] = (short)f2bf(pa1.w);
        af1[0] = (short)f2bf(pa2.x); af1[1] = (short)f2bf(pa2.y);
        af1[2] = (short)f2bf(pa2.z); af1[3] = (short)f2bf(pa2.w);
        af1[4] = (short)f2bf(pa3.x); af1[5] = (short)f2bf(pa3.y);
        af1[6] = (short)f2bf(pa3.z); af1[7] = (short)f2bf(pa3.w);

        const unsigned short* bt = bbase + (size_t)t * 16384;
        // chunk c (c=0..7): kk2 = c>>2, jj = c&3, cols j = jj*4+jx
#pragma unroll
        for (int jx = 0; jx < 4; jx++)
            bch[0][jx] = *(const bf16x8*)(bt + jx * 128);
#pragma unroll
        for (int jx = 0; jx < 4; jx++)
            bch[1][jx] = *(const bf16x8*)(bt + 512 + jx * 128);

#pragma unroll
        for (int c = 0; c < 8; c++) {
            if (c < 6) {   // issue chunk c+2 into bch[(c+2)%3]
                const int cc  = c + 2;
                const unsigned short* p = bt + (cc >> 2) * 8192 + (cc & 3) * 512;
#pragma unroll
                for (int jx = 0; jx < 4; jx++)
                    bch[cc % 3][jx] = *(const bf16x8*)(p + jx * 128);
            }
            if (c == 6 && t < 7) {   // next A AFTER all B issues -> counted waits
                const float* an = arow + (t + 1) * 64;
                pa0 = *(const float4*)an;        pa1 = *(const float4*)(an + 4);
                pa2 = *(const float4*)(an + 32); pa3 = *(const float4*)(an + 36);
            }
            // consume chunk c (wait leaves later chunks + pa in flight)
#pragma unroll
            for (int jx = 0; jx < 4; jx++) {
                if ((c >> 2) == 0)
                    acc[(c & 3) * 4 + jx] = __builtin_amdgcn_mfma_f32_16x16x32_bf16(
                        af0, bch[c % 3][jx], acc[(c & 3) * 4 + jx], 0, 0, 0);
                else
                    acc[(c & 3) * 4 + jx] = __builtin_amdgcn_mfma_f32_16x16x32_bf16(
                        af1, bch[c % 3][jx], acc[(c & 3) * 4 + jx], 0, 0, 0);
            }
        }
    }

    // C/D layout: col = j*16 + lm, row = row0 + quad*4 + r; store bf16
#pragma unroll
    for (int j = 0; j < 16; j++) {
        const int gcol = j * 16 + lm;
#pragma unroll
        for (int r = 0; r < 4; r++) {
            const int grow = row0 + quad * 4 + r;
            Cb[(size_t)grow * HD + gcol] = f2bf(acc[j][r]);
        }
    }

    // fused el/er: wave owns full rows; head h = j>>2.
    // al[j] = attn_l[col(j,lm)]; reduce over the 16-lane lm group.
    {
        float al[16], ar[16];
#pragma unroll
        for (int j = 0; j < 16; j++) {
            al[j] = attn_l[j * 16 + lm];
            ar[j] = attn_r[j * 16 + lm];
        }
#pragma unroll
        for (int r = 0; r < 4; r++) {
            float sl[4], sr[4];
#pragma unroll
            for (int h = 0; h < 4; h++) {
                float a = 0.f, b = 0.f;
#pragma unroll
                for (int jj = 0; jj < 4; jj++) {
                    a += acc[h * 4 + jj][r] * al[h * 4 + jj];
                    b += acc[h * 4 + jj][r] * ar[h * 4 + jj];
                }
#pragma unroll
                for (int off = 8; off > 0; off >>= 1) {
                    a += __shfl_xor(a, off);
                    b += __shfl_xor(b, off);
                }
                sl[h] = a; sr[h] = b;
            }
            if (lm == 0) {
                const int grow = row0 + quad * 4 + r;
                *(float4*)(el + (size_t)grow * NH) =
                    make_float4(sl[0], sl[1], sl[2], sl[3]);
                *(float4*)(er + (size_t)grow * NH) =
                    make_float4(sr[0], sr[1], sr[2], sr[3]);
            }
        }
    }
}

// ---------------- edge placement into padded ELL: ONE 16B record per edge -----
// Record (int4): .x = src node, .y = fp16(w0)|fp16(w1)<<16, .z = fp16(w2)|..,
// .w unused. Single scattered 16B store (4 records/line). (byte-identical r8)
__device__ __forceinline__ float lrelu_exp(float x) {
    float y = fmaxf(x, NEG * x);
    return fminf(__expf(y), 60000.f);   // fp16-safe (overflow prob ~1e-9)
}

__global__ __launch_bounds__(256) void place_kernel(const int* __restrict__ src,
                                                    const int* __restrict__ dst,
                                                    const float* __restrict__ el,
                                                    const float* __restrict__ er,
                                                    int* __restrict__ counts,
                                                    int4* __restrict__ recs) {
    int e = blockIdx.x * blockDim.x + threadIdx.x;
    if (e >= N_EDGES) return;
    int u = src[e], v = dst[e];
    float4 l = *(const float4*)(el + (size_t)u * NH);
    float4 r = *(const float4*)(er + (size_t)v * NH);
    float w0 = lrelu_exp(l.x + r.x);
    float w1 = lrelu_exp(l.y + r.y);
    float w2 = lrelu_exp(l.z + r.z);
    float w3 = lrelu_exp(l.w + r.w);
    int4 rec;
    rec.x = u;
    rec.y = (int)(((unsigned)f2h(w1) << 16) | (unsigned)f2h(w0));
    rec.z = (int)(((unsigned)f2h(w3) << 16) | (unsigned)f2h(w2));
    rec.w = 0;
    int j = atomicAdd(&counts[v], 1);
    if (j < MAXDEG) recs[(size_t)v * MAXDEG + j] = rec;
}

// ---------------- aggregation: one wave per dst, slim record loads ------------
// (byte-identical to round 8)
__global__ __launch_bounds__(256) void agg_kernel(const unsigned short* __restrict__ ftb,
                                                  const int4* __restrict__ recs,
                                                  const int* __restrict__ counts,
                                                  float* __restrict__ out) {
    int wv   = (blockIdx.x * blockDim.x + threadIdx.x) >> 6;  // node id
    int lane = threadIdx.x & 63;
    if (wv >= N_NODES) return;

    int deg = counts[wv];
    deg = (deg > MAXDEG) ? MAXDEG : deg;
    const int h    = lane >> 4;
    const int sh   = (h & 1) * 16;       // loop-invariant weight shift
    const int wsel = 1 + (h >> 1);       // loop-invariant weight dword index
    const size_t foff = (size_t)lane * 4;
    const unsigned* rp = (const unsigned*)(recs + (size_t)wv * MAXDEG);

    float4 acc = make_float4(0.f, 0.f, 0.f, 0.f);
    float dsum = 0.f;

    const int n8 = deg >> 3;   // full 8-edge blocks
    for (int b = 0; b < n8; b++) {
        const unsigned* q = rp + b * 32;   // 8 records x 4 dwords
        unsigned u0 = q[0],  p0 = q[0  + wsel];
        unsigned u1 = q[4],  p1 = q[4  + wsel];
        unsigned u2 = q[8],  p2 = q[8  + wsel];
        unsigned u3 = q[12], p3 = q[12 + wsel];
        unsigned u4 = q[16], p4 = q[16 + wsel];
        unsigned u5 = q[20], p5 = q[20 + wsel];
        unsigned u6 = q[24], p6 = q[24 + wsel];
        unsigned u7 = q[28], p7 = q[28 + wsel];
        ushort4 f0 = *(const ushort4*)(ftb + (size_t)u0 * HD + foff);
        ushort4 f1 = *(const ushort4*)(ftb + (size_t)u1 * HD + foff);
        ushort4 f2 = *(const ushort4*)(ftb + (size_t)u2 * HD + foff);
        ushort4 f3 = *(const ushort4*)(ftb + (size_t)u3 * HD + foff);
        ushort4 f4 = *(const ushort4*)(ftb + (size_t)u4 * HD + foff);
        ushort4 f5 = *(const ushort4*)(ftb + (size_t)u5 * HD + foff);
        ushort4 f6 = *(const ushort4*)(ftb + (size_t)u6 * HD + foff);
        ushort4 f7 = *(const ushort4*)(ftb + (size_t)u7 * HD + foff);
        float w0 = h2f((unsigned short)((p0 >> sh) & 0xFFFFu));
        float w1 = h2f((unsigned short)((p1 >> sh) & 0xFFFFu));
        float w2 = h2f((unsigned short)((p2 >> sh) & 0xFFFFu));
        float w3 = h2f((unsigned short)((p3 >> sh) & 0xFFFFu));
        float w4 = h2f((unsigned short)((p4 >> sh) & 0xFFFFu));
        float w5 = h2f((unsigned short)((p5 >> sh) & 0xFFFFu));
        float w6 = h2f((unsigned short)((p6 >> sh) & 0xFFFFu));
        float w7 = h2f((unsigned short)((p7 >> sh) & 0xFFFFu));
        acc.x += w0 * bf2f(f0.x) + w1 * bf2f(f1.x) + w2 * bf2f(f2.x) + w3 * bf2f(f3.x)
               + w4 * bf2f(f4.x) + w5 * bf2f(f5.x) + w6 * bf2f(f6.x) + w7 * bf2f(f7.x);
        acc.y += w0 * bf2f(f0.y) + w1 * bf2f(f1.y) + w2 * bf2f(f2.y) + w3 * bf2f(f3.y)
               + w4 * bf2f(f4.y) + w5 * bf2f(f5.y) + w6 * bf2f(f6.y) + w7 * bf2f(f7.y);
        acc.z += w0 * bf2f(f0.z) + w1 * bf2f(f1.z) + w2 * bf2f(f2.z) + w3 * bf2f(f3.z)
               + w4 * bf2f(f4.z) + w5 * bf2f(f5.z) + w6 * bf2f(f6.z) + w7 * bf2f(f7.z);
        acc.w += w0 * bf2f(f0.w) + w1 * bf2f(f1.w) + w2 * bf2f(f2.w) + w3 * bf2f(f3.w)
               + w4 * bf2f(f4.w) + w5 * bf2f(f5.w) + w6 * bf2f(f6.w) + w7 * bf2f(f7.w);
        dsum += ((w0 + w1) + (w2 + w3)) + ((w4 + w5) + (w6 + w7));
    }
    // predicated-parallel tail (1..7 edges); pad slots are in-bounds (ELL)
    {
        const int p0i = n8 * 8;
        const int rem = deg - p0i;
        if (rem > 0) {
            const unsigned* q = rp + p0i * 4;
            unsigned u0 = q[0];
            unsigned u1 = (1 < rem) ? q[4]  : u0;
            unsigned u2 = (2 < rem) ? q[8]  : u0;
            unsigned u3 = (3 < rem) ? q[12] : u0;
            unsigned u4 = (4 < rem) ? q[16] : u0;
            unsigned u5 = (5 < rem) ? q[20] : u0;
            unsigned u6 = (6 < rem) ? q[24] : u0;
            unsigned p0 = q[0 + wsel];
            unsigned p1 = (1 < rem) ? q[4  + wsel] : 0u;
            unsigned p2 = (2 < rem) ? q[8  + wsel] : 0u;
            unsigned p3 = (3 < rem) ? q[12 + wsel] : 0u;
            unsigned p4 = (4 < rem) ? q[16 + wsel] : 0u;
            unsigned p5 = (5 < rem) ? q[20 + wsel] : 0u;
            unsigned p6 = (6 < rem) ? q[24 + wsel] : 0u;
            ushort4 f0 = *(const ushort4*)(ftb + (size_t)u0 * HD + foff);
            ushort4 f1 = *(const ushort4*)(ftb + (size_t)u1 * HD + foff);
            ushort4 f2 = *(const ushort4*)(ftb + (size_t)u2 * HD + foff);
            ushort4 f3 = *(const ushort4*)(ftb + (size_t)u3 * HD + foff);
            ushort4 f4 = *(const ushort4*)(ftb + (size_t)u4 * HD + foff);
            ushort4 f5 = *(const ushort4*)(ftb + (size_t)u5 * HD + foff);
            ushort4 f6 = *(const ushort4*)(ftb + (size_t)u6 * HD + foff);
            float w0 = h2f((unsigned short)((p0 >> sh) & 0xFFFFu));
            float w1 = h2f((unsigned short)((p1 >> sh) & 0xFFFFu));
            float w2 = h2f((unsigned short)((p2 >> sh) & 0xFFFFu));
            float w3 = h2f((unsigned short)((p3 >> sh) & 0xFFFFu));
            float w4 = h2f((unsigned short)((p4 >> sh) & 0xFFFFu));
            float w5 = h2f((unsigned short)((p5 >> sh) & 0xFFFFu));
            float w6 = h2f((unsigned short)((p6 >> sh) & 0xFFFFu));
            acc.x += w0 * bf2f(f0.x) + w1 * bf2f(f1.x) + w2 * bf2f(f2.x) + w3 * bf2f(f3.x)
                   + w4 * bf2f(f4.x) + w5 * bf2f(f5.x) + w6 * bf2f(f6.x);
            acc.y += w0 * bf2f(f0.y) + w1 * bf2f(f1.y) + w2 * bf2f(f2.y) + w3 * bf2f(f3.y)
                   + w4 * bf2f(f4.y) + w5 * bf2f(f5.y) + w6 * bf2f(f6.y);
            acc.z += w0 * bf2f(f0.z) + w1 * bf2f(f1.z) + w2 * bf2f(f2.z) + w3 * bf2f(f3.z)
                   + w4 * bf2f(f4.z) + w5 * bf2f(f5.z) + w6 * bf2f(f6.z);
            acc.w += w0 * bf2f(f0.w) + w1 * bf2f(f1.w) + w2 * bf2f(f2.w) + w3 * bf2f(f3.w)
                   + w4 * bf2f(f4.w) + w5 * bf2f(f5.w) + w6 * bf2f(f6.w);
            dsum += ((w0 + w1) + (w2 + w3)) + ((w4 + w5) + w6);
        }
    }

    float inv = (dsum > 0.f) ? (1.f / dsum) : 0.f;
    acc.x *= inv; acc.y *= inv; acc.z *= inv; acc.w *= inv;
    *(float4*)(out + (size_t)wv * HD + foff) = acc;
}

// ---------------- launch ----------------
extern "C" void kernel_launch(void* const* d_in, const int* in_sizes, int n_in,
                              void* d_out, int out_size, void* d_ws, size_t ws_size,
                              hipStream_t stream) {
    const float* feat   = (const float*)d_in[0];
    const float* W      = (const float*)d_in[1];
    const float* attn_l = (const float*)d_in[2];
    const float* attn_r = (const float*)d_in[3];
    const int*   src    = (const int*)d_in[4];
    const int*   dst    = (const int*)d_in[5];
    float* out = (float*)d_out;

    char* p = (char*)d_ws;
    auto alloc = [&](size_t bytes) -> char* {
        char* r = p;
        p += (bytes + 255) & ~(size_t)255;
        return r;
    };
    unsigned short* ftb    = (unsigned short*)alloc((size_t)N_NODES * HD * 2);      // 25.6 MB
    unsigned short* WtbT   = (unsigned short*)alloc((size_t)IN_F * HD * 2);         // 0.26 MB
    float*          el     = (float*)alloc((size_t)N_NODES * NH * 4);               // 0.8 MB
    float*          er     = (float*)alloc((size_t)N_NODES * NH * 4);               // 0.8 MB
    int4*           recs   = (int4*)alloc((size_t)N_NODES * MAXDEG * 16);           // 51.2 MB
    int*            counts = (int*)alloc((size_t)N_NODES * 4);                      // 0.2 MB

    // 1. setup: zero counts + W -> WtbT granule-major bf16
    setup_kernel<<<NZB + (IN_F * HD + 255) / 256, 256, 0, stream>>>(W, WtbT, counts);
    // 2. ftb = bf16(feat @ W) + fused el/er (barrier-free, LDS-free, per-wave)
    gemm_kernel<<<(NWAVES + 3) / 4, 256, 0, stream>>>(feat, WtbT, attn_l, attn_r,
                                                      ftb, el, er);
    // 3. edge scores + ELL placement (one 16B record per edge)
    place_kernel<<<(N_EDGES + 255) / 256, 256, 0, stream>>>(src, dst, el, er,
                                                            counts, recs);
    // 4. aggregate per destination node (normalization fused)
    agg_kernel<<<(N_NODES + 3) / 4, 256, 0, stream>>>(ftb, recs, counts, out);
}

// Round 10
// 308.229 us; speedup vs baseline: 1.0634x; 1.0634x over previous
//
#include <hip/hip_runtime.h>
#include <hip/hip_fp16.h>

#define N_NODES 50000
#define N_EDGES 800000
#define IN_F    512
#define NH      4
#define DH      64
#define HD      256   // NH*DH
#define NEG     0.2f
#define MAXDEG  64    // Poisson(16) max degree bound: P(any node > 64) ~ e^-40 * 5e4 ~ 0

typedef __attribute__((ext_vector_type(8))) short bf16x8;
typedef __attribute__((ext_vector_type(4))) float f32x4;

__device__ __forceinline__ unsigned short f2bf(float x) {
    unsigned u = __float_as_uint(x);
    unsigned r = (u + 0x7FFFu + ((u >> 16) & 1u)) >> 16;  // RNE
    return (unsigned short)r;
}
__device__ __forceinline__ float bf2f(unsigned short b) {
    return __uint_as_float((unsigned)b << 16);
}
__device__ __forceinline__ unsigned short f2h(float x) {
    __half h = __float2half_rn(x);
    return *(unsigned short*)&h;
}
__device__ __forceinline__ float h2f(unsigned short us) {
    __half h = *(__half*)&us;
    return __half2float(h);
}

// ---------------- setup: zero counts + W -> WtbT (chunked + XOR-swizzled) -----
// WtbT layout: chunk (t, cb) = (k/64, n/128), 16KB contiguous each. Within a
// chunk the 16B granule for (local col nl, k-granule g) sits at linear granule
// nl*8 + (g ^ (nl&7)). DMA stages the chunk linearly; ds_read applies the same
// XOR -> bank-spread (r2/r7-verified pattern).
#define NZB ((N_NODES + 255) / 256)   // 196 zero chunks
__global__ __launch_bounds__(256) void setup_kernel(const float* __restrict__ W,
                                                    unsigned short* __restrict__ WtbT,
                                                    int* __restrict__ counts) {
    int b = blockIdx.x;
    if (b < NZB) {
        int i = b * 256 + threadIdx.x;
        if (i < N_NODES) counts[i] = 0;
    } else {
        int i = (b - NZB) * 256 + threadIdx.x;   // over 512*256
        if (i < IN_F * HD) {
            int k = i >> 8;        // 0..511
            int n = i & 255;       // 0..255
            int t  = k >> 6;       // k-tile
            int kk = k & 63;
            int g  = kk >> 3;      // 8-elem granule within tile
            int w8 = kk & 7;
            int cb = n >> 7;       // 128-col chunk
            int nl = n & 127;
            WtbT[((size_t)t * 2 + cb) * 8192 + (nl * 8 + (g ^ (nl & 7))) * 8 + w8]
                = f2bf(W[i]);
        }
    }
}

// ---------------- bf16 MFMA GEMM: ftb = bf16(feat @ W), el/er fused -----------
// 64x128 tile (grid 782 x 2), 4 waves: wave w owns rows (w>>1)*32..+31 and the
// 64-col half (w&1) == one head. acc[2][4] (32 VGPR).
// Pipeline (T3/T4, counted vmcnt + RAW s_barrier -- __syncthreads would drain
// vmcnt(0) and expose the ~900cy HBM A latency every tile, the r0-r8 stall):
//   iter t: STAGE_B(t+1) DMA -> B_s dbuf; LOAD_A(t+2) -> regs (depth 2,
//   clamped/branchless so vmcnt depth is wave-uniform); compute(t);
//   cvt A(t+1)->A_s dbuf (compiler auto-wait = counted vmcnt(8));
//   asm vmcnt(4) (retire B DMA, LEAVE A(t+2) in flight) + lgkmcnt(0);
//   s_barrier; sched_barrier(0)  [rule 18].
// LDS 51.2KB -> 3 blocks/CU (12 waves, was 8 at r7's 73KB).
#define LDPA 72   // padded LDS row stride in shorts
__global__ __launch_bounds__(256) void gemm_kernel(const float* __restrict__ A,
                                                   const unsigned short* __restrict__ WtbT,
                                                   const float* __restrict__ attn_l,
                                                   const float* __restrict__ attn_r,
                                                   unsigned short* __restrict__ Cb,
                                                   float* __restrict__ el,
                                                   float* __restrict__ er) {
    __shared__ short A_s[2][64][LDPA];    // 18.4 KB
    __shared__ short B_s[2][8192];        // 32 KB (dbuf, 128 cols x 64 k)

    const int tid  = threadIdx.x;
    const int lane = tid & 63;
    const int w    = tid >> 6;
    const int lm   = lane & 15;
    const int quad = lane >> 4;
    const int row0 = blockIdx.x * 64;
    const int cb   = blockIdx.y;          // 128-col chunk

    const int srow = tid >> 3;            // 0..31
    const int sc8  = (tid & 7) * 8;

    f32x4  acc[2][4] = {};
    float4 pa[2][4];

#define LOAD_A(KT, P)                                                          \
    {                                                                          \
        int g0 = row0 + srow; g0 = (g0 < N_NODES) ? g0 : (N_NODES - 1);        \
        const float* ap0 = A + (size_t)g0 * IN_F + (KT) + sc8;                 \
        pa[P][0] = *(const float4*)ap0; pa[P][1] = *(const float4*)(ap0 + 4);  \
        int g1 = row0 + 32 + srow; g1 = (g1 < N_NODES) ? g1 : (N_NODES - 1);   \
        const float* ap1 = A + (size_t)g1 * IN_F + (KT) + sc8;                 \
        pa[P][2] = *(const float4*)ap1; pa[P][3] = *(const float4*)(ap1 + 4);  \
    }

#define STAGE_B(T, BUF)                                                         \
    {                                                                           \
        const char* gsrc = (const char*)(WtbT + ((size_t)(T) * 2 + cb) * 8192)  \
                           + tid * 16;                                          \
        char* ldst = (char*)&B_s[BUF][0] + tid * 16;                            \
        _Pragma("unroll")                                                       \
        for (int s = 0; s < 4; s++)                                             \
            __builtin_amdgcn_global_load_lds(                                   \
                (const __attribute__((address_space(1))) unsigned int*)(gsrc + s * 4096), \
                (__attribute__((address_space(3))) unsigned int*)(ldst + s * 4096),       \
                16, 0, 0);                                                      \
    }

#define CVT_STORE(P, BUF)                                                      \
    {                                                                          \
        bf16x8 s;                                                              \
        s[0] = (short)f2bf(pa[P][0].x); s[1] = (short)f2bf(pa[P][0].y);        \
        s[2] = (short)f2bf(pa[P][0].z); s[3] = (short)f2bf(pa[P][0].w);        \
        s[4] = (short)f2bf(pa[P][1].x); s[5] = (short)f2bf(pa[P][1].y);        \
        s[6] = (short)f2bf(pa[P][1].z); s[7] = (short)f2bf(pa[P][1].w);        \
        *(bf16x8*)(&A_s[BUF][srow][sc8]) = s;                                  \
        s[0] = (short)f2bf(pa[P][2].x); s[1] = (short)f2bf(pa[P][2].y);        \
        s[2] = (short)f2bf(pa[P][2].z); s[3] = (short)f2bf(pa[P][2].w);        \
        s[4] = (short)f2bf(pa[P][3].x); s[5] = (short)f2bf(pa[P][3].y);        \
        s[6] = (short)f2bf(pa[P][3].z); s[7] = (short)f2bf(pa[P][3].w);        \
        *(bf16x8*)(&A_s[BUF][32 + srow][sc8]) = s;                             \
    }

    // prologue: A(0) first (oldest in queue), then B(0) DMA, cvt A(0)
    // (auto-wait vmcnt(4): counted, leaves B(0)), A(1), retire B(0), barrier.
    LOAD_A(0, 0);
    STAGE_B(0, 0);
    CVT_STORE(0, 0);
    LOAD_A(64, 1);
    asm volatile("s_waitcnt vmcnt(4) lgkmcnt(0)" ::: "memory");
    __builtin_amdgcn_s_barrier();
    __builtin_amdgcn_sched_barrier(0);

#pragma unroll
    for (int t = 0; t < 8; t++) {
        const int cur = t & 1;
        if (t < 7) STAGE_B(t + 1, cur ^ 1);          // B(t+1) -> other buf
        if (t < 6) LOAD_A((t + 2) * 64, t & 1);      // A(t+2) into freed pa

        // compute(t): LDS only (lgkm waits), vmem stays in flight
#pragma unroll
        for (int kk2 = 0; kk2 < 2; kk2++) {
            bf16x8 af[2], bfr[4];
#pragma unroll
            for (int i = 0; i < 2; i++)
                af[i] = *(const bf16x8*)(
                    &A_s[cur][(w >> 1) * 32 + i * 16 + lm][kk2 * 32 + quad * 8]);
#pragma unroll
            for (int j = 0; j < 4; j++) {
                int nl = (w & 1) * 64 + j * 16 + lm;
                int g  = kk2 * 4 + quad;
                int p  = nl * 8 + (g ^ (lm & 7));
                bfr[j] = *(const bf16x8*)(&B_s[cur][p * 8]);
            }
#pragma unroll
            for (int i = 0; i < 2; i++)
#pragma unroll
                for (int j = 0; j < 4; j++)
                    acc[i][j] = __builtin_amdgcn_mfma_f32_16x16x32_bf16(
                        af[i], bfr[j], acc[i][j], 0, 0, 0);
        }

        if (t < 7) {
            CVT_STORE((t + 1) & 1, cur ^ 1);   // auto-wait = counted vmcnt(8)
            if (t < 6)
                asm volatile("s_waitcnt vmcnt(4) lgkmcnt(0)" ::: "memory");
            else
                asm volatile("s_waitcnt vmcnt(0) lgkmcnt(0)" ::: "memory");
            __builtin_amdgcn_s_barrier();
            __builtin_amdgcn_sched_barrier(0);
        }
    }
#undef LOAD_A
#undef STAGE_B
#undef CVT_STORE

    // C/D layout: col = lane&15, row = quad*4 + reg; store bf16
#pragma unroll
    for (int i = 0; i < 2; i++) {
#pragma unroll
        for (int j = 0; j < 4; j++) {
            int gcol = cb * 128 + (w & 1) * 64 + j * 16 + lm;
#pragma unroll
            for (int r = 0; r < 4; r++) {
                int grow = row0 + (w >> 1) * 32 + i * 16 + quad * 4 + r;
                if (grow < N_NODES)
                    Cb[(size_t)grow * HD + gcol] = f2bf(acc[i][j][r]);
            }
        }
    }

    // fused el/er: wave's 64 cols == head h = cb*2 + (w&1)
    {
        const int h = cb * 2 + (w & 1);
        float al[4], ar[4];
#pragma unroll
        for (int j = 0; j < 4; j++) {
            al[j] = attn_l[h * DH + j * 16 + lm];
            ar[j] = attn_r[h * DH + j * 16 + lm];
        }
#pragma unroll
        for (int i = 0; i < 2; i++) {
#pragma unroll
            for (int r = 0; r < 4; r++) {
                float sl = 0.f, sr = 0.f;
#pragma unroll
                for (int j = 0; j < 4; j++) {
                    sl += acc[i][j][r] * al[j];
                    sr += acc[i][j][r] * ar[j];
                }
#pragma unroll
                for (int off = 8; off > 0; off >>= 1) {
                    sl += __shfl_xor(sl, off);
                    sr += __shfl_xor(sr, off);
                }
                if (lm == 0) {
                    int grow = row0 + (w >> 1) * 32 + i * 16 + quad * 4 + r;
                    if (grow < N_NODES) {
                        el[(size_t)grow * NH + h] = sl;
                        er[(size_t)grow * NH + h] = sr;
                    }
                }
            }
        }
    }
}

// ---------------- edge placement into padded ELL: ONE 16B record per edge -----
// Record (int4): .x = src node, .y = fp16(w0)|fp16(w1)<<16, .z = fp16(w2)|..,
// .w unused. Single scattered 16B store (4 records/line). (byte-identical r8)
__device__ __forceinline__ float lrelu_exp(float x) {
    float y = fmaxf(x, NEG * x);
    return fminf(__expf(y), 60000.f);   // fp16-safe (overflow prob ~1e-9)
}

__global__ __launch_bounds__(256) void place_kernel(const int* __restrict__ src,
                                                    const int* __restrict__ dst,
                                                    const float* __restrict__ el,
                                                    const float* __restrict__ er,
                                                    int* __restrict__ counts,
                                                    int4* __restrict__ recs) {
    int e = blockIdx.x * blockDim.x + threadIdx.x;
    if (e >= N_EDGES) return;
    int u = src[e], v = dst[e];
    float4 l = *(const float4*)(el + (size_t)u * NH);
    float4 r = *(const float4*)(er + (size_t)v * NH);
    float w0 = lrelu_exp(l.x + r.x);
    float w1 = lrelu_exp(l.y + r.y);
    float w2 = lrelu_exp(l.z + r.z);
    float w3 = lrelu_exp(l.w + r.w);
    int4 rec;
    rec.x = u;
    rec.y = (int)(((unsigned)f2h(w1) << 16) | (unsigned)f2h(w0));
    rec.z = (int)(((unsigned)f2h(w3) << 16) | (unsigned)f2h(w2));
    rec.w = 0;
    int j = atomicAdd(&counts[v], 1);
    if (j < MAXDEG) recs[(size_t)v * MAXDEG + j] = rec;
}

// ---------------- aggregation: one wave per dst, slim record loads ------------
// (byte-identical to round 8/9)
__global__ __launch_bounds__(256) void agg_kernel(const unsigned short* __restrict__ ftb,
                                                  const int4* __restrict__ recs,
                                                  const int* __restrict__ counts,
                                                  float* __restrict__ out) {
    int wv   = (blockIdx.x * blockDim.x + threadIdx.x) >> 6;  // node id
    int lane = threadIdx.x & 63;
    if (wv >= N_NODES) return;

    int deg = counts[wv];
    deg = (deg > MAXDEG) ? MAXDEG : deg;
    const int h    = lane >> 4;
    const int sh   = (h & 1) * 16;       // loop-invariant weight shift
    const int wsel = 1 + (h >> 1);       // loop-invariant weight dword index
    const size_t foff = (size_t)lane * 4;
    const unsigned* rp = (const unsigned*)(recs + (size_t)wv * MAXDEG);

    float4 acc = make_float4(0.f, 0.f, 0.f, 0.f);
    float dsum = 0.f;

    const int n8 = deg >> 3;   // full 8-edge blocks
    for (int b = 0; b < n8; b++) {
        const unsigned* q = rp + b * 32;   // 8 records x 4 dwords
        unsigned u0 = q[0],  p0 = q[0  + wsel];
        unsigned u1 = q[4],  p1 = q[4  + wsel];
        unsigned u2 = q[8],  p2 = q[8  + wsel];
        unsigned u3 = q[12], p3 = q[12 + wsel];
        unsigned u4 = q[16], p4 = q[16 + wsel];
        unsigned u5 = q[20], p5 = q[20 + wsel];
        unsigned u6 = q[24], p6 = q[24 + wsel];
        unsigned u7 = q[28], p7 = q[28 + wsel];
        ushort4 f0 = *(const ushort4*)(ftb + (size_t)u0 * HD + foff);
        ushort4 f1 = *(const ushort4*)(ftb + (size_t)u1 * HD + foff);
        ushort4 f2 = *(const ushort4*)(ftb + (size_t)u2 * HD + foff);
        ushort4 f3 = *(const ushort4*)(ftb + (size_t)u3 * HD + foff);
        ushort4 f4 = *(const ushort4*)(ftb + (size_t)u4 * HD + foff);
        ushort4 f5 = *(const ushort4*)(ftb + (size_t)u5 * HD + foff);
        ushort4 f6 = *(const ushort4*)(ftb + (size_t)u6 * HD + foff);
        ushort4 f7 = *(const ushort4*)(ftb + (size_t)u7 * HD + foff);
        float w0 = h2f((unsigned short)((p0 >> sh) & 0xFFFFu));
        float w1 = h2f((unsigned short)((p1 >> sh) & 0xFFFFu));
        float w2 = h2f((unsigned short)((p2 >> sh) & 0xFFFFu));
        float w3 = h2f((unsigned short)((p3 >> sh) & 0xFFFFu));
        float w4 = h2f((unsigned short)((p4 >> sh) & 0xFFFFu));
        float w5 = h2f((unsigned short)((p5 >> sh) & 0xFFFFu));
        float w6 = h2f((unsigned short)((p6 >> sh) & 0xFFFFu));
        float w7 = h2f((unsigned short)((p7 >> sh) & 0xFFFFu));
        acc.x += w0 * bf2f(f0.x) + w1 * bf2f(f1.x) + w2 * bf2f(f2.x) + w3 * bf2f(f3.x)
               + w4 * bf2f(f4.x) + w5 * bf2f(f5.x) + w6 * bf2f(f6.x) + w7 * bf2f(f7.x);
        acc.y += w0 * bf2f(f0.y) + w1 * bf2f(f1.y) + w2 * bf2f(f2.y) + w3 * bf2f(f3.y)
               + w4 * bf2f(f4.y) + w5 * bf2f(f5.y) + w6 * bf2f(f6.y) + w7 * bf2f(f7.y);
        acc.z += w0 * bf2f(f0.z) + w1 * bf2f(f1.z) + w2 * bf2f(f2.z) + w3 * bf2f(f3.z)
               + w4 * bf2f(f4.z) + w5 * bf2f(f5.z) + w6 * bf2f(f6.z) + w7 * bf2f(f7.z);
        acc.w += w0 * bf2f(f0.w) + w1 * bf2f(f1.w) + w2 * bf2f(f2.w) + w3 * bf2f(f3.w)
               + w4 * bf2f(f4.w) + w5 * bf2f(f5.w) + w6 * bf2f(f6.w) + w7 * bf2f(f7.w);
        dsum += ((w0 + w1) + (w2 + w3)) + ((w4 + w5) + (w6 + w7));
    }
    // predicated-parallel tail (1..7 edges); pad slots are in-bounds (ELL)
    {
        const int p0i = n8 * 8;
        const int rem = deg - p0i;
        if (rem > 0) {
            const unsigned* q = rp + p0i * 4;
            unsigned u0 = q[0];
            unsigned u1 = (1 < rem) ? q[4]  : u0;
            unsigned u2 = (2 < rem) ? q[8]  : u0;
            unsigned u3 = (3 < rem) ? q[12] : u0;
            unsigned u4 = (4 < rem) ? q[16] : u0;
            unsigned u5 = (5 < rem) ? q[20] : u0;
            unsigned u6 = (6 < rem) ? q[24] : u0;
            unsigned p0 = q[0 + wsel];
            unsigned p1 = (1 < rem) ? q[4  + wsel] : 0u;
            unsigned p2 = (2 < rem) ? q[8  + wsel] : 0u;
            unsigned p3 = (3 < rem) ? q[12 + wsel] : 0u;
            unsigned p4 = (4 < rem) ? q[16 + wsel] : 0u;
            unsigned p5 = (5 < rem) ? q[20 + wsel] : 0u;
            unsigned p6 = (6 < rem) ? q[24 + wsel] : 0u;
            ushort4 f0 = *(const ushort4*)(ftb + (size_t)u0 * HD + foff);
            ushort4 f1 = *(const ushort4*)(ftb + (size_t)u1 * HD + foff);
            ushort4 f2 = *(const ushort4*)(ftb + (size_t)u2 * HD + foff);
            ushort4 f3 = *(const ushort4*)(ftb + (size_t)u3 * HD + foff);
            ushort4 f4 = *(const ushort4*)(ftb + (size_t)u4 * HD + foff);
            ushort4 f5 = *(const ushort4*)(ftb + (size_t)u5 * HD + foff);
            ushort4 f6 = *(const ushort4*)(ftb + (size_t)u6 * HD + foff);
            float w0 = h2f((unsigned short)((p0 >> sh) & 0xFFFFu));
            float w1 = h2f((unsigned short)((p1 >> sh) & 0xFFFFu));
            float w2 = h2f((unsigned short)((p2 >> sh) & 0xFFFFu));
            float w3 = h2f((unsigned short)((p3 >> sh) & 0xFFFFu));
            float w4 = h2f((unsigned short)((p4 >> sh) & 0xFFFFu));
            float w5 = h2f((unsigned short)((p5 >> sh) & 0xFFFFu));
            float w6 = h2f((unsigned short)((p6 >> sh) & 0xFFFFu));
            acc.x += w0 * bf2f(f0.x) + w1 * bf2f(f1.x) + w2 * bf2f(f2.x) + w3 * bf2f(f3.x)
                   + w4 * bf2f(f4.x) + w5 * bf2f(f5.x) + w6 * bf2f(f6.x);
            acc.y += w0 * bf2f(f0.y) + w1 * bf2f(f1.y) + w2 * bf2f(f2.y) + w3 * bf2f(f3.y)
                   + w4 * bf2f(f4.y) + w5 * bf2f(f5.y) + w6 * bf2f(f6.y);
            acc.z += w0 * bf2f(f0.z) + w1 * bf2f(f1.z) + w2 * bf2f(f2.z) + w3 * bf2f(f3.z)
                   + w4 * bf2f(f4.z) + w5 * bf2f(f5.z) + w6 * bf2f(f6.z);
            acc.w += w0 * bf2f(f0.w) + w1 * bf2f(f1.w) + w2 * bf2f(f2.w) + w3 * bf2f(f3.w)
                   + w4 * bf2f(f4.w) + w5 * bf2f(f5.w) + w6 * bf2f(f6.w);
            dsum += ((w0 + w1) + (w2 + w3)) + ((w4 + w5) + w6);
        }
    }

    float inv = (dsum > 0.f) ? (1.f / dsum) : 0.f;
    acc.x *= inv; acc.y *= inv; acc.z *= inv; acc.w *= inv;
    *(float4*)(out + (size_t)wv * HD + foff) = acc;
}

// ---------------- launch ----------------
extern "C" void kernel_launch(void* const* d_in, const int* in_sizes, int n_in,
                              void* d_out, int out_size, void* d_ws, size_t ws_size,
                              hipStream_t stream) {
    const float* feat   = (const float*)d_in[0];
    const float* W      = (const float*)d_in[1];
    const float* attn_l = (const float*)d_in[2];
    const float* attn_r = (const float*)d_in[3];
    const int*   src    = (const int*)d_in[4];
    const int*   dst    = (const int*)d_in[5];
    float* out = (float*)d_out;

    char* p = (char*)d_ws;
    auto alloc = [&](size_t bytes) -> char* {
        char* r = p;
        p += (bytes + 255) & ~(size_t)255;
        return r;
    };
    unsigned short* ftb    = (unsigned short*)alloc((size_t)N_NODES * HD * 2);      // 25.6 MB
    unsigned short* WtbT   = (unsigned short*)alloc((size_t)IN_F * HD * 2);         // 0.26 MB
    float*          el     = (float*)alloc((size_t)N_NODES * NH * 4);               // 0.8 MB
    float*          er     = (float*)alloc((size_t)N_NODES * NH * 4);               // 0.8 MB
    int4*           recs   = (int4*)alloc((size_t)N_NODES * MAXDEG * 16);           // 51.2 MB
    int*            counts = (int*)alloc((size_t)N_NODES * 4);                      // 0.2 MB

    // 1. setup: zero counts + W -> WtbT chunked/swizzled bf16
    setup_kernel<<<NZB + (IN_F * HD + 255) / 256, 256, 0, stream>>>(W, WtbT, counts);
    // 2. ftb = bf16(feat @ W) + fused el/er (counted-vmcnt raw-barrier pipeline)
    {
        dim3 g((N_NODES + 63) / 64, 2);
        gemm_kernel<<<g, 256, 0, stream>>>(feat, WtbT, attn_l, attn_r, ftb, el, er);
    }
    // 3. edge scores + ELL placement (one 16B record per edge)
    place_kernel<<<(N_EDGES + 255) / 256, 256, 0, stream>>>(src, dst, el, er,
                                                            counts, recs);
    // 4. aggregate per destination node (normalization fused)
    agg_kernel<<<(N_NODES + 3) / 4, 256, 0, stream>>>(ftb, recs, counts, out);
}